// Round 8
// baseline (958.994 us; speedup 1.0000x reference)
//
#include <hip/hip_runtime.h>
#include <hip/hip_bf16.h>

// GCN_20332375179669: 2-layer graph attention, B=8 N=2048 H=256 A=64.
// R8: ONE persistent kernel (grid=1024 = 4 blocks/CU guaranteed by
// __launch_bounds__(256,4): LDS 24.6KB*4=98KB<160KB, VGPR capped 128 ->
// 16 waves/CU). Manual grid barrier (atomic counter + device fences;
// counters zeroed by a tiny pre-kernel since ws is re-poisoned). Phase 1
// overlaps embed GEMM + weight pack with the whole 134MB csr scan via an
// atomic work queue; then qkv1 / attn1 / qkv2 / attn2+head, no launch gaps.
// R5's cooperative launch failed because coop launches aren't graph-
// capturable; plain launches are.

#define NB 8
#define NN 2048
#define ROWS (NB * NN)
#define MAXD 64     // Binomial(2048,0.01): mean 20.5, sd 4.5 -> ~9.7 sigma
#define GRID 1024
#define TPB 256

typedef float f4 __attribute__((ext_vector_type(4)));
typedef _Float16 hf;
typedef _Float16 hx2 __attribute__((ext_vector_type(2)));
typedef _Float16 hx4 __attribute__((ext_vector_type(4)));
typedef _Float16 hx8 __attribute__((ext_vector_type(8)));
typedef unsigned int u32;
typedef unsigned short u16;
typedef u16 us8 __attribute__((ext_vector_type(8)));

__device__ __forceinline__ float sigmoidf_(float x) { return 1.f / (1.f + __expf(-x)); }
__device__ __forceinline__ hx2 u2h(u32 u) { union { u32 u; hx2 h; } c; c.u = u; return c.h; }
__device__ __forceinline__ float dot2_(hx2 a, hx2 b, float c) {
#if __has_builtin(__builtin_amdgcn_fdot2)
    return __builtin_amdgcn_fdot2(a, b, c, false);
#else
    return c + (float)a.x * (float)b.x + (float)a.y * (float)b.y;
#endif
}
__device__ __forceinline__ u32 permlo_(u32 hi, u32 lo) { return __builtin_amdgcn_perm(hi, lo, 0x05040100u); }
__device__ __forceinline__ u32 permhi_(u32 hi, u32 lo) { return __builtin_amdgcn_perm(hi, lo, 0x07060302u); }

struct Args {
    const int *x, *cue;
    const float *adj, *emb, *Wh, *bh, *Wq, *Wk, *Wv, *gcb, *Wc, *bc;
    hf *hB, *qkvB, *Wpt;
    int *deg, *nbr;
    int *ctrl;        // ctrl[0]=barrier, ctrl[1]=csr work queue
    float *out;
};

union SBig {
    struct { float As[32 * 64]; float Ws[32 * 128]; } e;   // 24576 B (embed)
    struct { u16 As[64 * 40]; u16 Bs[128 * 40]; } q;       // 15360 B (qkv)
};
struct SCtl { int srow; int cnt; };

// ---- grid barrier: all GRID blocks co-resident by construction.
__device__ __forceinline__ void gsync(int* bar, int target) {
    __syncthreads();
    if (threadIdx.x == 0) {
        __threadfence();                       // release prior writes
        atomicAdd(bar, 1);
        int guard = 0;
        while (__hip_atomic_load(bar, __ATOMIC_RELAXED, __HIP_MEMORY_SCOPE_AGENT) < target
               && ++guard < (1 << 25))
            __builtin_amdgcn_s_sleep(2);
        __threadfence();                       // acquire others' writes
    }
    __syncthreads();
}

__global__ __launch_bounds__(64) void k_init(int* ctrl) {
    if (threadIdx.x < 2) ctrl[threadIdx.x] = 0;
}

// ---- pack Wq|Wk|Wv -> Wpt[c*256+f] fp16 (transposed, k-contiguous)
__device__ __forceinline__ void pack_w(const Args& A, int pb, int t) {
    int base = pb * 256 + t;
#pragma unroll
    for (int r = 0; r < 4; ++r) {
        int i = base + r * 96 * 256;
        int c = i >> 8, f = i & 255;
        float v;
        if (c < 64)       v = A.Wq[f * 64 + c];
        else if (c < 128) v = A.Wk[f * 64 + (c - 64)];
        else              v = A.Wv[f * 256 + (c - 128)];
        A.Wpt[i] = (hf)v;
    }
}

// ---- embed GEMM tile: h[64 x 128] = relu([emb[x],cue] @ Wh + bh)
__device__ void embed_tile(const Args& A, int tile, int t, SBig& sb) {
    int row0 = (tile >> 1) * 64, col0 = (tile & 1) * 128;
    int srow = t & 63, skg = t >> 6;
    int swc = (t & 31) * 4, swk = t >> 5;
    int tx = t & 15, ty = t >> 4;
    int xr = A.x[row0 + srow];
    float cv = (float)A.cue[row0 + srow];
    const float* er = A.emb + (size_t)xr * 255;

    float acc[4][8];
#pragma unroll
    for (int i = 0; i < 4; ++i)
#pragma unroll
        for (int j = 0; j < 8; ++j) acc[i][j] = 0.f;

    for (int kc = 0; kc < 256; kc += 32) {
        int kb = skg * 8;
#pragma unroll
        for (int u = 0; u < 8; ++u) {
            int f = kc + kb + u;
            sb.e.As[(kb + u) * 64 + srow] = (f < 255) ? er[f] : cv;
        }
#pragma unroll
        for (int r = 0; r < 4; ++r) {
            int kk = swk + r * 8;
            f4 w = *(const f4*)(A.Wh + (size_t)(kc + kk) * 256 + col0 + swc);
            *(f4*)&sb.e.Ws[kk * 128 + swc] = w;
        }
        __syncthreads();
#pragma unroll
        for (int k = 0; k < 32; ++k) {
            f4 av = *(f4*)&sb.e.As[k * 64 + ty * 4];
            f4 w0 = *(f4*)&sb.e.Ws[k * 128 + tx * 8];
            f4 w1 = *(f4*)&sb.e.Ws[k * 128 + tx * 8 + 4];
            float a[4] = {av.x, av.y, av.z, av.w};
            float w[8] = {w0.x, w0.y, w0.z, w0.w, w1.x, w1.y, w1.z, w1.w};
#pragma unroll
            for (int i = 0; i < 4; ++i)
#pragma unroll
                for (int j = 0; j < 8; ++j) acc[i][j] += a[i] * w[j];
        }
        __syncthreads();
    }
    f4 b0 = *(const f4*)(A.bh + col0 + tx * 8);
    f4 b1 = *(const f4*)(A.bh + col0 + tx * 8 + 4);
    float bb[8] = {b0.x, b0.y, b0.z, b0.w, b1.x, b1.y, b1.z, b1.w};
#pragma unroll
    for (int i = 0; i < 4; ++i) {
        int row = row0 + ty * 4 + i;
        hx8 o;
#pragma unroll
        for (int j = 0; j < 8; ++j) o[j] = (hf)fmaxf(acc[i][j] + bb[j], 0.f);
        *(hx8*)(A.hB + (size_t)row * 256 + col0 + tx * 8) = o;
    }
}

// ---- csr scan of one adjacency row (2048 floats, f4 NT loads)
__device__ __forceinline__ void csr_row(const Args& A, int row, int t, int* cnt) {
    const f4* ar4 = (const f4*)(A.adj + (size_t)row * NN);
    if (t == 0) *cnt = 0;
    __syncthreads();
    int* nr = A.nbr + (size_t)row * MAXD;
#pragma unroll
    for (int it = 0; it < 2; ++it) {
        int idx = it * 256 + t;
        f4 vv = __builtin_nontemporal_load(ar4 + idx);
        if (vv.x > 0.f) { int p = atomicAdd(cnt, 1); if (p < MAXD) nr[p] = idx * 4 + 0; }
        if (vv.y > 0.f) { int p = atomicAdd(cnt, 1); if (p < MAXD) nr[p] = idx * 4 + 1; }
        if (vv.z > 0.f) { int p = atomicAdd(cnt, 1); if (p < MAXD) nr[p] = idx * 4 + 2; }
        if (vv.w > 0.f) { int p = atomicAdd(cnt, 1); if (p < MAXD) nr[p] = idx * 4 + 3; }
    }
    __syncthreads();
    if (t == 0) A.deg[row] = (*cnt < MAXD) ? *cnt : MAXD;
}

// ---- qkv MFMA tile (64 rows x 128 cols), LDS-staged, fp16 16x16x32
__device__ void qkv_tile(const Args& A, int tile, int t, SBig& sb) {
    int col0 = (tile % 3) * 128, row0 = (tile / 3) * 64;
    int wave = t >> 6, lane = t & 63;
    int l16 = lane & 15, quad = lane >> 4;
    f4 acc[4][2];
#pragma unroll
    for (int i = 0; i < 4; ++i) { acc[i][0] = (f4){0,0,0,0}; acc[i][1] = (f4){0,0,0,0}; }
    int ar = t >> 2, ao = (t & 3) * 8;
    int bcs = t >> 1, bo = (t & 1) * 16;
    const u16* hB16 = (const u16*)A.hB;
    const u16* Wp16 = (const u16*)A.Wpt;

    for (int kc = 0; kc < 256; kc += 32) {
        us8 av  = *(const us8*)(hB16 + (size_t)(row0 + ar) * 256 + kc + ao);
        us8 bv0 = *(const us8*)(Wp16 + (size_t)(col0 + bcs) * 256 + kc + bo);
        us8 bv1 = *(const us8*)(Wp16 + (size_t)(col0 + bcs) * 256 + kc + bo + 8);
        __syncthreads();               // prior iter frag reads done
        *(us8*)&sb.q.As[ar * 40 + ao] = av;
        *(us8*)&sb.q.Bs[bcs * 40 + bo] = bv0;
        *(us8*)&sb.q.Bs[bcs * 40 + bo + 8] = bv1;
        __syncthreads();
        hx8 afr[4], bfr[2];
#pragma unroll
        for (int mt = 0; mt < 4; ++mt)
            afr[mt] = *(hx8*)&sb.q.As[(mt * 16 + l16) * 40 + quad * 8];
#pragma unroll
        for (int nt = 0; nt < 2; ++nt)
            bfr[nt] = *(hx8*)&sb.q.Bs[((wave * 2 + nt) * 16 + l16) * 40 + quad * 8];
#pragma unroll
        for (int mt = 0; mt < 4; ++mt)
#pragma unroll
            for (int nt = 0; nt < 2; ++nt)
                acc[mt][nt] = __builtin_amdgcn_mfma_f32_16x16x32_f16(
                    afr[mt], bfr[nt], acc[mt][nt], 0, 0, 0);
    }
#pragma unroll
    for (int mt = 0; mt < 4; ++mt)
#pragma unroll
        for (int nt = 0; nt < 2; ++nt) {
            int c = col0 + (wave * 2 + nt) * 16 + l16;
#pragma unroll
            for (int reg = 0; reg < 4; ++reg) {
                int r = row0 + mt * 16 + quad * 4 + reg;
                A.qkvB[(size_t)r * 384 + c] = (hf)acc[mt][nt][reg];
            }
        }
}

// ---- sparse attention for one row (one wave); R7 3-phase exact softmax
__device__ void attn_row(const Args& A, int row, int lane, bool write_out) {
    int d = A.deg[row];
    f4 g4 = *(const f4*)(A.gcb + lane * 4);
    float h0, h1, h2c, h3;
    if (d == 0) {
        h0 = sigmoidf_(g4.x); h1 = sigmoidf_(g4.y);
        h2c = sigmoidf_(g4.z); h3 = sigmoidf_(g4.w);
    } else {
        const hf* qkvB = A.qkvB;
        const int* jl = A.nbr + (size_t)row * MAXD;
        int bbase = row & ~(NN - 1);
        int jlane = jl[lane < d ? lane : 0];
        int sub = lane & 3;

        // phase 1: logits, quad per edge, 16 edges per pass
        const uint4* qp = (const uint4*)(qkvB + (size_t)row * 384 + sub * 16);
        uint4 qa = qp[0], qb = qp[1];
        float pp[4] = {-1e30f, -1e30f, -1e30f, -1e30f};
#pragma unroll
        for (int pi = 0; pi < 4; ++pi) {
            if (pi * 16 < d) {
                int e = pi * 16 + (lane >> 2);
                int j = __shfl(jlane, e < d ? e : 0);
                float p = -1e30f;
                if (e < d) {
                    const uint4* kp = (const uint4*)(qkvB + (size_t)(bbase + j) * 384 + 64 + sub * 16);
                    uint4 ka = kp[0], kb = kp[1];
                    p = dot2_(u2h(ka.x), u2h(qa.x),
                        dot2_(u2h(ka.y), u2h(qa.y),
                        dot2_(u2h(ka.z), u2h(qa.z),
                        dot2_(u2h(ka.w), u2h(qa.w),
                        dot2_(u2h(kb.x), u2h(qb.x),
                        dot2_(u2h(kb.y), u2h(qb.y),
                        dot2_(u2h(kb.z), u2h(qb.z),
                        dot2_(u2h(kb.w), u2h(qb.w), 0.f))))))));
                }
                p += __shfl_xor(p, 1);
                p += __shfl_xor(p, 2);
                pp[pi] = p;
            }
        }
        int src = (lane & 15) << 2;
        float t0 = __shfl(pp[0], src), t1 = __shfl(pp[1], src);
        float t2 = __shfl(pp[2], src), t3 = __shfl(pp[3], src);
        int hi = lane >> 4;
        float pe = hi == 0 ? t0 : hi == 1 ? t1 : hi == 2 ? t2 : t3;
        if (lane >= d) pe = -1e30f;

        // phase 2: exact softmax across the wave, pre-normalized
        float mx = pe;
#pragma unroll
        for (int off = 32; off; off >>= 1) mx = fmaxf(mx, __shfl_xor(mx, off));
        float wv = __expf(pe - mx);
        float sv = wv;
#pragma unroll
        for (int off = 32; off; off >>= 1) sv += __shfl_xor(sv, off);
        float wn = wv * (1.f / sv);

        // phase 3: AV — all gathers independent, dot2/perm packed math
        f4 a = {0, 0, 0, 0};
        for (int g = 0; g < d; g += 4) {
            float w0 = __shfl(wn, g),     w1 = __shfl(wn, g + 1);
            float w2 = __shfl(wn, g + 2), w3 = __shfl(wn, g + 3);
            int j0 = __shfl(jlane, g),     j1 = __shfl(jlane, g + 1);
            int j2 = __shfl(jlane, g + 2), j3 = __shfl(jlane, g + 3);
            hx2 w01, w23;
            w01.x = (hf)w0; w01.y = (hf)w1;
            w23.x = (hf)w2; w23.y = (hf)w3;
            uint2 v0 = *(const uint2*)(qkvB + (size_t)(bbase + j0) * 384 + 128 + lane * 4);
            uint2 v1 = *(const uint2*)(qkvB + (size_t)(bbase + j1) * 384 + 128 + lane * 4);
            uint2 v2 = *(const uint2*)(qkvB + (size_t)(bbase + j2) * 384 + 128 + lane * 4);
            uint2 v3 = *(const uint2*)(qkvB + (size_t)(bbase + j3) * 384 + 128 + lane * 4);
            a.x = dot2_(u2h(permlo_(v1.x, v0.x)), w01,
                  dot2_(u2h(permlo_(v3.x, v2.x)), w23, a.x));
            a.y = dot2_(u2h(permhi_(v1.x, v0.x)), w01,
                  dot2_(u2h(permhi_(v3.x, v2.x)), w23, a.y));
            a.z = dot2_(u2h(permlo_(v1.y, v0.y)), w01,
                  dot2_(u2h(permlo_(v3.y, v2.y)), w23, a.z));
            a.w = dot2_(u2h(permhi_(v1.y, v0.y)), w01,
                  dot2_(u2h(permhi_(v3.y, v2.y)), w23, a.w));
        }
        h0 = sigmoidf_(a.x + g4.x);
        h1 = sigmoidf_(a.y + g4.y);
        h2c = sigmoidf_(a.z + g4.z);
        h3 = sigmoidf_(a.w + g4.w);
    }
    if (!write_out) {
        hx4 o; o.x = (hf)h0; o.y = (hf)h1; o.z = (hf)h2c; o.w = (hf)h3;
        *(hx4*)(A.hB + (size_t)row * 256 + lane * 4) = o;
    } else {
        f4 wc0 = *(const f4*)(A.Wc + lane * 8);
        f4 wc1 = *(const f4*)(A.Wc + lane * 8 + 4);
        float pa = h0 * wc0.x + h1 * wc0.z + h2c * wc1.x + h3 * wc1.z;
        float pb = h0 * wc0.y + h1 * wc0.w + h2c * wc1.y + h3 * wc1.w;
#pragma unroll
        for (int off = 32; off; off >>= 1) {
            pa += __shfl_xor(pa, off);
            pb += __shfl_xor(pb, off);
        }
        if (lane == 0) {
            float l0 = pa + A.bc[0], l1 = pb + A.bc[1];
            float m2 = fmaxf(l0, l1);
            float e0 = __expf(l0 - m2), e1 = __expf(l1 - m2);
            float inv2 = 1.f / (e0 + e1);
            A.out[(size_t)row * 2 + 0] = e0 * inv2;
            A.out[(size_t)row * 2 + 1] = e1 * inv2;
        }
    }
}

// ============================================================ mega kernel
__global__ __launch_bounds__(TPB, 4) void k_mega(Args A) {
    __shared__ SBig sb;
    __shared__ SCtl sc;
    int bid = blockIdx.x, t = threadIdx.x;
    int wave = t >> 6, lane = t & 63;
    int batch = bid & 7, idx = bid >> 3;   // XCD-affine batch mapping

    // ---- P1: embed + pack + full csr scan via atomic work queue
    if (bid < 512) embed_tile(A, bid, t, sb);
    else if (bid < 608) pack_w(A, bid - 512, t);
    for (;;) {
        __syncthreads();
        if (t == 0) sc.srow = atomicAdd(A.ctrl + 1, 4);
        __syncthreads();
        int r0 = sc.srow;
        if (r0 >= ROWS) break;
        int rn = (r0 + 4 < ROWS) ? r0 + 4 : ROWS;
        for (int r = r0; r < rn; ++r) csr_row(A, r, t, &sc.cnt);
    }
    gsync(A.ctrl, GRID);

    // ---- P2: qkv layer 1
    if (bid < 768) qkv_tile(A, bid, t, sb);
    gsync(A.ctrl, 2 * GRID);

    // ---- P3: attn layer 1
    for (int k2 = 0; k2 < 4; ++k2)
        attn_row(A, batch * NN + idx * 16 + wave * 4 + k2, lane, false);
    gsync(A.ctrl, 3 * GRID);

    // ---- P4: qkv layer 2
    if (bid < 768) qkv_tile(A, bid, t, sb);
    gsync(A.ctrl, 4 * GRID);

    // ---- P5: attn layer 2 + classifier head
    for (int k2 = 0; k2 < 4; ++k2)
        attn_row(A, batch * NN + idx * 16 + wave * 4 + k2, lane, true);
}

extern "C" void kernel_launch(void* const* d_in, const int* in_sizes, int n_in,
                              void* d_out, int out_size, void* d_ws, size_t ws_size,
                              hipStream_t stream) {
    Args A;
    A.x   = (const int*)d_in[0];
    A.cue = (const int*)d_in[1];
    A.adj = (const float*)d_in[2];
    A.emb = (const float*)d_in[3];
    A.Wh  = (const float*)d_in[4];
    A.bh  = (const float*)d_in[5];
    A.Wq  = (const float*)d_in[6];
    A.Wk  = (const float*)d_in[7];
    A.Wv  = (const float*)d_in[8];
    A.gcb = (const float*)d_in[9];
    A.Wc  = (const float*)d_in[10];
    A.bc  = (const float*)d_in[11];
    A.out = (float*)d_out;

    // workspace carve (~24.3 MB)
    char* w = (char*)d_ws;
    A.hB   = (hf*)w;   w += (size_t)ROWS * 256 * 2;   // 8 MB
    A.qkvB = (hf*)w;   w += (size_t)ROWS * 384 * 2;   // 12 MB
    A.Wpt  = (hf*)w;   w += (size_t)384 * 256 * 2;    // 192 KB
    A.deg  = (int*)w;  w += (size_t)ROWS * 4;         // 64 KB
    A.nbr  = (int*)w;  w += (size_t)ROWS * MAXD * 4;  // 4 MB
    A.ctrl = (int*)w;                                  // 8 B (barrier + queue)

    k_init<<<1, 64, 0, stream>>>(A.ctrl);
    k_mega<<<GRID, TPB, 0, stream>>>(A);
}